// Round 12
// baseline (96.496 us; speedup 1.0000x reference)
//
#include <hip/hip_runtime.h>

typedef float f4 __attribute__((ext_vector_type(4)));

#define IN_H 128
#define IN_W 128
#define NCH  128
#define UPN  256

constexpr int SEG  = 8;    // output rows per block
constexpr int COLS = 32;   // output cols per block
constexpr int CH   = 32;   // channels per block
constexpr int IRW  = 14;   // input row window  (i0-3 .. i0+10)
constexpr int ICW  = 38;   // input col window  (jc0-3 .. jc0+34)
constexpr int NT4  = IRW * ICW * CH / 4;   // 4256 16-byte staging tasks

__device__ __forceinline__ float cubic_k(float x) {
  // Keys cubic, a = -0.5, x >= 0
  float r = 0.f;
  if (x < 1.f)      r = (1.5f * x - 2.5f) * x * x + 1.f;
  else if (x < 2.f) r = ((-0.5f * x + 2.5f) * x - 4.f) * x + 2.f;
  return r;
}

// global -> LDS direct copy, 16 B per lane (LDS dest wave-uniform base).
#define GLDS(g, l)                                                         \
  __builtin_amdgcn_global_load_lds(                                        \
      (const __attribute__((address_space(1))) void*)(g),                  \
      (__attribute__((address_space(3))) void*)(l), 16, 0, 0)

__global__ __launch_bounds__(256, 2)
void actfilter_kernel(const float* __restrict__ x, float* __restrict__ out) {
  __shared__ __align__(16) float xin[IRW][ICW][CH];  // 68096 B (unchanged)
  __shared__ __align__(16) float upw[UPN][4];        //  4096 B
  __shared__ __align__(16) float dww[IN_H][8];       //  4096 B

  const int tid = threadIdx.x;

  // XCD swizzle: batch image -> XCD; ch-chunks + neighbor tiles adjacent.
  int bid  = blockIdx.x;
  int work = ((bid & 7) << 8) | (bid >> 3);
  const int b   = work >> 8;
  const int rs  = (work >> 4) & 15;
  const int cs  = (work >> 2) & 3;
  const int chs = work & 3;
  const int i0  = rs * SEG;
  const int jc0 = cs * COLS;
  const int c0  = chs * CH;
  const int mlo = i0 - 3;
  const int mhi = i0 + 10;

  const float* xbase = x   + (size_t)b * IN_H * IN_W * NCH;
  float*       obase = out + (size_t)b * IN_H * IN_W * NCH;

  // ---- issue ALL staging loads first (latency hides under table build) ----
  {
    char* lbase = (char*)&xin[0][0][0] + ((tid >> 6) << 10);
#pragma unroll
    for (int pass = 0; pass < 17; ++pass) {
      int t = tid + pass * 256;
      if (t < NT4) {
        int row   = t / 304;            // 304 = ICW*CH/4 tasks per input row
        int rem   = t - row * 304;
        int col   = rem >> 3;
        int piece = rem & 7;
        int gr = min(max(mlo + row, 0), IN_H - 1);
        int gc = min(max(jc0 - 3 + col, 0), IN_W - 1);
        const float* gp = xbase + ((size_t)gr * IN_W + gc) * NCH + c0 + piece * 4;
        GLDS(gp, lbase + pass * 4096);
      }
    }
  }

  // ---- weight tables (VALU work overlapping the loads) ----
  {
    int o = tid;                       // 0..255 upsample positions
    int k = o >> 1;
    int base = (o & 1) ? (k - 1) : (k - 2);
    float s = 0.5f * o - 0.25f;
    float w[4]; float sum = 0.f;
#pragma unroll
    for (int t = 0; t < 4; ++t) {
      int tap = base + t;
      float wt = (tap >= 0 && tap < IN_H) ? cubic_k(fabsf(s - (float)tap)) : 0.f;
      w[t] = wt; sum += wt;
    }
    float inv = 1.f / sum;
#pragma unroll
    for (int t = 0; t < 4; ++t) upw[o][t] = w[t] * inv;
  }
  if (tid < IN_H) {
    int j = tid;                       // 0..127 downsample positions
    float s = 2.f * j + 0.5f;
    float w[8]; float sum = 0.f;
#pragma unroll
    for (int t = 0; t < 8; ++t) {
      int tap = 2 * j - 3 + t;
      float wt = (tap >= 0 && tap < UPN) ? cubic_k(0.5f * fabsf(s - (float)tap)) : 0.f;
      w[t] = wt; sum += wt;
    }
    float inv = 1.f / sum;
#pragma unroll
    for (int t = 0; t < 8; ++t) dww[j][t] = w[t] * inv;
  }

  __syncthreads();   // the ONLY barrier: xin + tables ready

  // ---- per-thread mapping: col-quad cp (0..7), channel e (0..31) ----
  // 4 out-cols x 1 ch per thread: u-window 14 cols per 4 out-cols (1.75x
  // halo overhead vs 2.5x at 2-col ownership) -> ~20% fewer VALU insts.
  const int cp = tid >> 5;
  const int e  = tid & 31;
  const int j0 = jc0 + 4 * cp;         // output cols j0 .. j0+3

  // W-upsample weights for this thread's 14 u-cols (edge renorm baked in)
  f4 wvv[14];
#pragma unroll
  for (int c = 0; c < 14; ++c) {
    int cu = min(max(2 * j0 - 3 + c, 0), UPN - 1);
    wvv[c] = *(const f4*)&upw[cu][0];
  }
  // W-downsample weights for cols j0 .. j0+3
  float dw[4][8];
#pragma unroll
  for (int q = 0; q < 4; ++q) {
    f4 lo = *(const f4*)&dww[j0 + q][0];
    f4 hi = *(const f4*)&dww[j0 + q][4];
#pragma unroll
    for (int t = 0; t < 4; ++t) { dw[q][t] = lo[t]; dw[q][t + 4] = hi[t]; }
  }

  const int r_lo = max(2 * i0 - 3, 0);
  const int r_hi = min(2 * i0 + 2 * SEG + 2, UPN - 1);

  // Interior 2x-bicubic H-up weights are exact dyadic constants (sum = 1);
  // selected statically by r parity. Only r<3 / r>252 (rs 0/15 blocks) need
  // the renormalized table -> wave-uniform fallback branch.
  const f4 whE = {-0.0234375f, 0.2265625f, 0.8671875f, -0.0703125f};
  const f4 whO = {-0.0703125f, 0.8671875f, 0.2265625f, -0.0234375f};

  float tw[4][14];                     // W-upsampled row ring (static-indexed)
  float acc[4][4];                     // [slot][out-col q] H-down accumulators
#pragma unroll
  for (int s2 = 0; s2 < 4; ++s2)
#pragma unroll
    for (int q = 0; q < 4; ++q) acc[s2][q] = 0.f;

#define DO_R(RV, WHC, S0, S1, S2, S3)                                        \
  do {                                                                       \
    int r = (RV);                                                            \
    if (r >= r_lo && r <= r_hi) {                                            \
      f4 wh = (WHC);                                                         \
      if (r < 3 || r > 252) wh = *(const f4*)&upw[r][0];                     \
      float lv[14];                                                          \
      _Pragma("unroll")                                                      \
      for (int c = 0; c < 14; ++c) {                                         \
        float hu = wh.x * tw[S0][c] + wh.y * tw[S1][c]                       \
                 + wh.z * tw[S2][c] + wh.w * tw[S3][c];                      \
        lv[c] = fmaxf(hu, 0.01f * hu);                                       \
      }                                                                      \
      float z[4];                                                            \
      _Pragma("unroll")                                                      \
      for (int q = 0; q < 4; ++q) {                                          \
        float zq = dw[q][0] * lv[2 * q];                                     \
        _Pragma("unroll")                                                    \
        for (int t = 1; t < 8; ++t) zq += dw[q][t] * lv[2 * q + t];          \
        z[q] = zq;                                                           \
      }                                                                      \
      int ilo = max(i0, (r - 3) >> 1);                                       \
      int ihi = min(i0 + SEG - 1, (r + 3) >> 1);                             \
      _Pragma("unroll")                                                      \
      for (int s = 0; s < 4; ++s) {                                          \
        int i = ilo + ((s - ilo) & 3);                                       \
        if (i <= ihi) {                                                      \
          float w = dww[i][r - 2 * i + 3];                                   \
          _Pragma("unroll")                                                  \
          for (int q = 0; q < 4; ++q) acc[s][q] += w * z[q];                 \
          bool done = (r == 2 * i + 4) ||                                    \
                      (r == UPN - 1 && 2 * i + 4 > UPN - 1);                 \
          if (done) {                                                        \
            float* dst = obase + ((size_t)i * IN_W + j0) * NCH + c0 + e;     \
            _Pragma("unroll")                                                \
            for (int q = 0; q < 4; ++q) {                                    \
              dst[q * NCH] = acc[s][q];                                      \
              acc[s][q] = 0.f;                                               \
            }                                                                \
          }                                                                  \
        }                                                                    \
      }                                                                      \
    }                                                                        \
  } while (0)

#define STEP(PH)                                                             \
  do {                                                                       \
    int m = mlo + mb + (PH);                                                 \
    if (m <= mhi) {                                                          \
      int ml = m - mlo;                                                      \
      float raw[10];                                                         \
      _Pragma("unroll")                                                      \
      for (int k = 0; k < 10; ++k)                                           \
        raw[k] = xin[ml][4 * cp + k][e];                                     \
      _Pragma("unroll")                                                      \
      for (int c = 0; c < 14; ++c) {                                         \
        tw[(PH) & 3][c] = wvv[c].x * raw[(c >> 1) + 0]                       \
                        + wvv[c].y * raw[(c >> 1) + 1]                       \
                        + wvv[c].z * raw[(c >> 1) + 2]                       \
                        + wvv[c].w * raw[(c >> 1) + 3];                      \
      }                                                                      \
      DO_R(2 * m - 3, whO, ((PH) + 1) & 3, ((PH) + 2) & 3, ((PH) + 3) & 3, (PH) & 3); \
      DO_R(2 * m - 2, whE, ((PH) + 1) & 3, ((PH) + 2) & 3, ((PH) + 3) & 3, (PH) & 3); \
    }                                                                        \
  } while (0)

  // 14 m-steps, unrolled in groups of 4 so ring slots are compile-time.
  for (int mb = 0; mb < 16; mb += 4) {
    STEP(0);
    STEP(1);
    STEP(2);
    STEP(3);
  }

#undef STEP
#undef DO_R
}

extern "C" void kernel_launch(void* const* d_in, const int* in_sizes, int n_in,
                              void* d_out, int out_size, void* d_ws, size_t ws_size,
                              hipStream_t stream) {
  const float* x = (const float*)d_in[0];
  float* out = (float*)d_out;
  actfilter_kernel<<<dim3(2048), dim3(256), 0, stream>>>(x, out);
}